// Round 6
// baseline (895.802 us; speedup 1.0000x reference)
//
#include <hip/hip_runtime.h>
#include <math.h>

// Problem constants (reference: T=16384, H=2048, E=256)
#define H_      2048
#define E_      256
#define T_TILE  16      // tokens per block
#define KC      32      // K-chunk staged in LDS (= 2 SSE 16-blocks)
#define TOPK    8
#define KGROUP  4

// LDS: GEMM fp32 staging unioned with the per-tile fp32 logit matrix.
// Transposed layout (as R4, known-good banks): w[k][expert], h[k][token].
struct GemmSmem {
    float w[KC][260];   // padded rows (1040 B, 16B-aligned)
    float h[KC][20];    // 80 B rows
};
union SMem {
    GemmSmem g;
    float logits[T_TILE][E_];   // 16 KB
};

__global__ __launch_bounds__(256, 4)
void router_kernel(const float* __restrict__ hp,
                   const float* __restrict__ wp,
                   const float* __restrict__ bp,
                   float* __restrict__ out, int T)
{
    __shared__ SMem sm;
    const int tid = threadIdx.x;
    const int t0  = blockIdx.x * T_TILE;
    const int eq  = tid & 63;   // expert quad: experts eq*4 .. eq*4+3
    const int wv  = tid >> 6;   // wave id == token quad: tokens wv*4 .. wv*4+3

    // Emulate numpy einsum's sum_of_products_contig_contig_outstride0_two
    // (baseline SSE, npyv vstep=4, muladd UNFUSED, x4-unrolled with REVERSED
    // chaining):  per SSE lane l (= k mod 4), per 16-elem block m:
    //   v[l] = p(m,0,l) + (p(m,1,l) + (p(m,2,l) + (p(m,3,l) + v[l])))
    // where p(m,j,l) = round(h[16m+4j+l] * w[16m+4j+l]); all adds rounded.
    // Final: logit = (v0+v1) + (v2+v3)   [SSE3 hadd tree]
    float v[4][4][4];   // [token i][expert j][sse lane l]
#pragma unroll
    for (int i = 0; i < 4; ++i)
#pragma unroll
        for (int j = 0; j < 4; ++j)
#pragma unroll
            for (int l = 0; l < 4; ++l) v[i][j][l] = 0.f;

    const int c  = tid & 7;    // float4 column within chunk (0..7)
    const int er = tid >> 3;   // expert row group (0..31)

    for (int ch = 0; ch < H_ / KC; ++ch) {
        const int k0 = ch * KC;

        // ---- stage h tile (transposed): threads 0..127
        if (tid < 128) {
            const int t  = tid >> 3;
            const int cc = tid & 7;
            float4 hv4 = *(const float4*)(hp + (size_t)(t0 + t) * H_ + k0 + cc * 4);
            sm.g.h[cc * 4 + 0][t] = hv4.x;
            sm.g.h[cc * 4 + 1][t] = hv4.y;
            sm.g.h[cc * 4 + 2][t] = hv4.z;
            sm.g.h[cc * 4 + 3][t] = hv4.w;
        }
        // ---- stage w tile (transposed): 8 expert rows per thread
#pragma unroll
        for (int r = 0; r < 8; ++r) {
            const int e = er + r * 32;
            float4 wv4 = *(const float4*)(wp + (size_t)e * H_ + k0 + c * 4);
            sm.g.w[c * 4 + 0][e] = wv4.x;
            sm.g.w[c * 4 + 1][e] = wv4.y;
            sm.g.w[c * 4 + 2][e] = wv4.z;
            sm.g.w[c * 4 + 3][e] = wv4.w;
        }
        __syncthreads();

        // ---- visit k in the einsum order: blocks ascending, j-desc within
        //      block (p3 added first), l = k mod 4 selects the SSE lane chain.
#pragma unroll
        for (int mb = 0; mb < 2; ++mb) {
#pragma unroll
            for (int jj = 3; jj >= 0; --jj) {
#pragma unroll
                for (int l = 0; l < 4; ++l) {
                    const int kk = mb * 16 + jj * 4 + l;
                    float4 hv = *(const float4*)(&sm.g.h[kk][wv * 4]); // broadcast
                    float4 wf = *(const float4*)(&sm.g.w[kk][eq * 4]);
                    v[0][0][l] = __fadd_rn(v[0][0][l], __fmul_rn(hv.x, wf.x));
                    v[0][1][l] = __fadd_rn(v[0][1][l], __fmul_rn(hv.x, wf.y));
                    v[0][2][l] = __fadd_rn(v[0][2][l], __fmul_rn(hv.x, wf.z));
                    v[0][3][l] = __fadd_rn(v[0][3][l], __fmul_rn(hv.x, wf.w));
                    v[1][0][l] = __fadd_rn(v[1][0][l], __fmul_rn(hv.y, wf.x));
                    v[1][1][l] = __fadd_rn(v[1][1][l], __fmul_rn(hv.y, wf.y));
                    v[1][2][l] = __fadd_rn(v[1][2][l], __fmul_rn(hv.y, wf.z));
                    v[1][3][l] = __fadd_rn(v[1][3][l], __fmul_rn(hv.y, wf.w));
                    v[2][0][l] = __fadd_rn(v[2][0][l], __fmul_rn(hv.z, wf.x));
                    v[2][1][l] = __fadd_rn(v[2][1][l], __fmul_rn(hv.z, wf.y));
                    v[2][2][l] = __fadd_rn(v[2][2][l], __fmul_rn(hv.z, wf.z));
                    v[2][3][l] = __fadd_rn(v[2][3][l], __fmul_rn(hv.z, wf.w));
                    v[3][0][l] = __fadd_rn(v[3][0][l], __fmul_rn(hv.w, wf.x));
                    v[3][1][l] = __fadd_rn(v[3][1][l], __fmul_rn(hv.w, wf.y));
                    v[3][2][l] = __fadd_rn(v[3][2][l], __fmul_rn(hv.w, wf.z));
                    v[3][3][l] = __fadd_rn(v[3][3][l], __fmul_rn(hv.w, wf.w));
                }
            }
        }
        __syncthreads();
    }

    // ---- hadd tree + dump fp32 logits into the unioned tile
#pragma unroll
    for (int i = 0; i < 4; ++i)
#pragma unroll
        for (int j = 0; j < 4; ++j)
            sm.logits[wv * 4 + i][eq * 4 + j] =
                __fadd_rn(__fadd_rn(v[i][j][0], v[i][j][1]),
                          __fadd_rn(v[i][j][2], v[i][j][3]));
    __syncthreads();

    // ================= routing: each wave handles its 4 tokens ==============
    const int lane = tid & 63;
    float* out_idx = out;                       // [T][8] indices as floats
    float* out_w   = out + (size_t)T * TOPK;    // [T][8] weights

    const float b0 = bp[lane * 4 + 0];
    const float b1 = bp[lane * 4 + 1];
    const float b2 = bp[lane * 4 + 2];
    const float b3 = bp[lane * 4 + 3];

    for (int tt = 0; tt < 4; ++tt) {
        const int tl = wv * 4 + tt;
        const int t  = t0 + tl;

        float4 lg = *(const float4*)(&sm.logits[tl][lane * 4]);
        // numpy graph: s = 1/(1+exp(-x)) with fp32 add and fp32 division;
        // exp in fp64, correctly rounded to fp32.
        const float E0 = (float)exp(-(double)lg.x);
        const float E1 = (float)exp(-(double)lg.y);
        const float E2 = (float)exp(-(double)lg.z);
        const float E3 = (float)exp(-(double)lg.w);
        const float s0 = __fdiv_rn(1.0f, __fadd_rn(1.0f, E0));
        const float s1 = __fdiv_rn(1.0f, __fadd_rn(1.0f, E1));
        const float s2 = __fdiv_rn(1.0f, __fadd_rn(1.0f, E2));
        const float s3 = __fdiv_rn(1.0f, __fadd_rn(1.0f, E3));
        // scores_for_choice = score + bias (fp32 add; bias == 0)
        const float f0 = s0 + b0, f1 = s1 + b1, f2 = s2 + b2, f3 = s3 + b3;

        // ---- per-lane top-2 of its 4 sfc values
        float a = fmaxf(f0, f1), b = fminf(f0, f1);
        if (f2 > a) { b = a; a = f2; } else b = fmaxf(b, f2);
        if (f3 > a) { b = a; a = f3; } else b = fmaxf(b, f3);
        // ---- reduce top-2 across the 8 lanes of this group
#pragma unroll
        for (int m = 1; m <= 4; m <<= 1) {
            float oa = __shfl_xor(a, m);
            float ob = __shfl_xor(b, m);
            float na, nb;
            if (a >= oa) { na = a;  nb = fmaxf(oa, b); }
            else         { na = oa; nb = fmaxf(a, ob); }
            a = na; b = nb;
        }
        const float gsc = a + b;   // group score (fp32)

        // gather all 8 group scores to every lane
        float g0 = __shfl(gsc,  0), g1 = __shfl(gsc,  8);
        float g2 = __shfl(gsc, 16), g3 = __shfl(gsc, 24);
        float g4 = __shfl(gsc, 32), g5 = __shfl(gsc, 40);
        float g6 = __shfl(gsc, 48), g7 = __shfl(gsc, 56);

        // ---- top-4 groups (stable: lower index wins ties via strict >)
        unsigned gmask = 0;
#pragma unroll
        for (int r = 0; r < KGROUP; ++r) {
            float best = g0; int bg = 0;
            if (g1 > best) { best = g1; bg = 1; }
            if (g2 > best) { best = g2; bg = 2; }
            if (g3 > best) { best = g3; bg = 3; }
            if (g4 > best) { best = g4; bg = 4; }
            if (g5 > best) { best = g5; bg = 5; }
            if (g6 > best) { best = g6; bg = 6; }
            if (g7 > best) { best = g7; bg = 7; }
            gmask |= (1u << bg);
            g0 = (bg == 0) ? -1.f : g0;  g1 = (bg == 1) ? -1.f : g1;
            g2 = (bg == 2) ? -1.f : g2;  g3 = (bg == 3) ? -1.f : g3;
            g4 = (bg == 4) ? -1.f : g4;  g5 = (bg == 5) ? -1.f : g5;
            g6 = (bg == 6) ? -1.f : g6;  g7 = (bg == 7) ? -1.f : g7;
        }

        // ---- masked sfc (unselected groups -> 0.0, matching np.where)
        const int  myg  = lane >> 3;
        const bool keep = (gmask >> myg) & 1u;
        float v0 = keep ? f0 : 0.f, v1 = keep ? f1 : 0.f;
        float v2 = keep ? f2 : 0.f, v3 = keep ? f3 : 0.f;

        // ---- top-8: 8 rounds of 64-lane butterfly argmax, fp32 values,
        //      exact-equality ties -> lower expert index (stable top_k)
        int   isel[TOPK];
        float ssel[TOPK];
#pragma unroll
        for (int r = 0; r < TOPK; ++r) {
            float bv = v0; int bj = 0; float bs = s0;
            if (v1 > bv) { bv = v1; bj = 1; bs = s1; }
            if (v2 > bv) { bv = v2; bj = 2; bs = s2; }
            if (v3 > bv) { bv = v3; bj = 3; bs = s3; }
            float cv = bv; int ci = lane * 4 + bj; float cs = bs;
#pragma unroll
            for (int m = 1; m < 64; m <<= 1) {
                float ov = __shfl_xor(cv, m);
                int   oi = __shfl_xor(ci, m);
                float os = __shfl_xor(cs, m);
                if (ov > cv || (ov == cv && oi < ci)) { cv = ov; ci = oi; cs = os; }
            }
            isel[r] = ci; ssel[r] = cs;
            if ((ci >> 2) == lane) {       // owner removes the winner
                const int sl = ci & 3;
                v0 = (sl == 0) ? -1.f : v0;
                v1 = (sl == 1) ? -1.f : v1;
                v2 = (sl == 2) ? -1.f : v2;
                v3 = (sl == 3) ? -1.f : v3;
            }
        }

        // ---- normalize + scale in fp32: w = (w / (sum + 1e-20)) * 2.5
        // np pairwise 8-sum: ((w0+w1)+(w2+w3)) + ((w4+w5)+(w6+w7))
        const float sum = __fadd_rn(
            __fadd_rn(__fadd_rn(ssel[0], ssel[1]), __fadd_rn(ssel[2], ssel[3])),
            __fadd_rn(__fadd_rn(ssel[4], ssel[5]), __fadd_rn(ssel[6], ssel[7])));
        const float denom = __fadd_rn(sum, 1e-20f);
        if (lane == 0) {
#pragma unroll
            for (int r = 0; r < TOPK; ++r) {
                out_idx[(size_t)t * TOPK + r] = (float)isel[r];
                out_w  [(size_t)t * TOPK + r] =
                    __fmul_rn(__fdiv_rn(ssel[r], denom), 2.5f);
            }
        }
    }
}

extern "C" void kernel_launch(void* const* d_in, const int* in_sizes, int n_in,
                              void* d_out, int out_size, void* d_ws, size_t ws_size,
                              hipStream_t stream) {
    const float* hs = (const float*)d_in[0];
    const float* w  = (const float*)d_in[1];
    const float* b  = (const float*)d_in[2];
    const int E = in_sizes[2];          // 256
    const int H = in_sizes[1] / E;      // 2048
    const int T = in_sizes[0] / H;      // 16384
    (void)n_in; (void)d_ws; (void)ws_size; (void)out_size; (void)E; (void)H;

    dim3 grid(T / T_TILE);
    router_kernel<<<grid, 256, 0, stream>>>(hs, w, b, (float*)d_out, T);
}

// Round 7
// 801.679 us; speedup vs baseline: 1.1174x; 1.1174x over previous
//
#include <hip/hip_runtime.h>
#include <math.h>

// Problem constants (reference: T=16384, H=2048, E=256)
#define H_      2048
#define E_      256
#define T_TILE  32      // tokens per block (8 per thread)
#define KC      32      // K-chunk staged in LDS (= 2 SSE 16-blocks)
#define TOPK    8
#define KGROUP  4

typedef float f2 __attribute__((ext_vector_type(2)));

// LDS: w expert-major rows (transposed staging, contiguous-1024B wave reads);
// h split into 4 SSE-lane planes so compute reads are scalar b32 broadcasts
// (verified-free on gfx950) and cannot be fused into b128 broadcasts.
struct GemmSmem {
    float w[KC][260];        // 33280 B, padded rows
    float h[4][T_TILE][9];   // [sse lane l][token][jgroup], 4608 B
};
union SMem {
    GemmSmem g;
    float logits[T_TILE][E_];   // 32 KB
};

__global__ __launch_bounds__(256, 2)
void router_kernel(const float* __restrict__ hp,
                   const float* __restrict__ wp,
                   const float* __restrict__ bp,
                   float* __restrict__ out, int T)
{
#pragma clang fp contract(off)
    __shared__ SMem sm;
    const int tid = threadIdx.x;
    const int t0  = blockIdx.x * T_TILE;
    const int eq  = tid & 63;   // expert quad: experts eq*4 .. eq*4+3
    const int wv  = tid >> 6;   // wave id: tokens wv*8 .. wv*8+7

    // numpy einsum sum_of_products emulation: per output, 4 independent
    // mod-4 chains (l = k%4), adds per 16-block in j-desc order, all mul/add
    // UNFUSED fp32. Chains packed in f2 pairs (l0,l1)/(l2,l3) -> v_pk_* ok
    // (IEEE-identical per component).
    f2 acc[8][4][2];   // [token i][expert j][pair]
#pragma unroll
    for (int i = 0; i < 8; ++i)
#pragma unroll
        for (int j = 0; j < 4; ++j) {
            acc[i][j][0] = (f2){0.f, 0.f};
            acc[i][j][1] = (f2){0.f, 0.f};
        }

    const int c  = tid & 7;    // float4 column within chunk (0..7)
    const int er = tid >> 3;   // expert row group (0..31) / token for h stage

    for (int ch = 0; ch < H_ / KC; ++ch) {
        const int k0 = ch * KC;

        // ---- stage h into l-planes: all 256 threads, one float4 each
        {
            const int t  = tid >> 3;     // 0..31
            const int jg = tid & 7;      // jgroup 0..7
            float4 hv4 = *(const float4*)(hp + (size_t)(t0 + t) * H_ + k0 + jg * 4);
            sm.g.h[0][t][jg] = hv4.x;
            sm.g.h[1][t][jg] = hv4.y;
            sm.g.h[2][t][jg] = hv4.z;
            sm.g.h[3][t][jg] = hv4.w;
        }
        // ---- stage w tile (transposed): 8 expert rows per thread
#pragma unroll
        for (int r = 0; r < 8; ++r) {
            const int e = er + r * 32;
            float4 wv4 = *(const float4*)(wp + (size_t)e * H_ + k0 + c * 4);
            sm.g.w[c * 4 + 0][e] = wv4.x;
            sm.g.w[c * 4 + 1][e] = wv4.y;
            sm.g.w[c * 4 + 2][e] = wv4.z;
            sm.g.w[c * 4 + 3][e] = wv4.w;
        }
        __syncthreads();

        // ---- compute: 16-blocks ascending, j-group descending within block
#pragma unroll
        for (int mb = 0; mb < 2; ++mb) {
#pragma unroll
            for (int jj = 3; jj >= 0; --jj) {
                const int jg = mb * 4 + jj;
                const int kb = mb * 16 + jj * 4;
                // w: 4 contiguous-1024B b128 wave reads (one per sse lane)
                float4 w0 = *(const float4*)(&sm.g.w[kb + 0][eq * 4]);
                float4 w1 = *(const float4*)(&sm.g.w[kb + 1][eq * 4]);
                float4 w2 = *(const float4*)(&sm.g.w[kb + 2][eq * 4]);
                float4 w3 = *(const float4*)(&sm.g.w[kb + 3][eq * 4]);
                // h: scalar b32 same-address broadcasts from the l-planes
                float hs0[8], hs1[8], hs2[8], hs3[8];
#pragma unroll
                for (int i = 0; i < 8; ++i) {
                    hs0[i] = sm.g.h[0][wv * 8 + i][jg];
                    hs1[i] = sm.g.h[1][wv * 8 + i][jg];
                    hs2[i] = sm.g.h[2][wv * 8 + i][jg];
                    hs3[i] = sm.g.h[3][wv * 8 + i][jg];
                }
                const float* wp0 = (const float*)&w0;
                const float* wp1 = (const float*)&w1;
                const float* wp2 = (const float*)&w2;
                const float* wp3 = (const float*)&w3;
#pragma unroll
                for (int i = 0; i < 8; ++i) {
                    const f2 hA = {hs0[i], hs1[i]};
                    const f2 hB = {hs2[i], hs3[i]};
#pragma unroll
                    for (int j = 0; j < 4; ++j) {
                        const f2 wA = {wp0[j], wp1[j]};
                        const f2 wB = {wp2[j], wp3[j]};
                        f2 pA = hA * wA;                 // unfused mul (RN)
                        f2 pB = hB * wB;
                        acc[i][j][0] = acc[i][j][0] + pA; // unfused add (RN)
                        acc[i][j][1] = acc[i][j][1] + pB;
                    }
                }
            }
        }
        __syncthreads();
    }

    // ---- hadd tree (v0+v1)+(v2+v3) + dump fp32 logits into unioned tile
#pragma unroll
    for (int i = 0; i < 8; ++i)
#pragma unroll
        for (int j = 0; j < 4; ++j)
            sm.logits[wv * 8 + i][eq * 4 + j] =
                ((acc[i][j][0].x + acc[i][j][0].y) +
                 (acc[i][j][1].x + acc[i][j][1].y));
    __syncthreads();

    // ================= routing: each wave handles its 8 tokens ==============
    const int lane = tid & 63;
    float* out_idx = out;                       // [T][8] indices as floats
    float* out_w   = out + (size_t)T * TOPK;    // [T][8] weights

    const float b0 = bp[lane * 4 + 0];
    const float b1 = bp[lane * 4 + 1];
    const float b2 = bp[lane * 4 + 2];
    const float b3 = bp[lane * 4 + 3];

    for (int tt = 0; tt < 8; ++tt) {
        const int tl = wv * 8 + tt;
        const int t  = t0 + tl;

        float4 lg = *(const float4*)(&sm.logits[tl][lane * 4]);
        // numpy graph: s = 1/(1+exp(-x)), fp32 add + fp32 division;
        // exp in fp64, correctly rounded to fp32.
        const float E0 = (float)exp(-(double)lg.x);
        const float E1 = (float)exp(-(double)lg.y);
        const float E2 = (float)exp(-(double)lg.z);
        const float E3 = (float)exp(-(double)lg.w);
        const float s0 = __fdiv_rn(1.0f, __fadd_rn(1.0f, E0));
        const float s1 = __fdiv_rn(1.0f, __fadd_rn(1.0f, E1));
        const float s2 = __fdiv_rn(1.0f, __fadd_rn(1.0f, E2));
        const float s3 = __fdiv_rn(1.0f, __fadd_rn(1.0f, E3));
        // scores_for_choice = score + bias (fp32 add; bias == 0)
        const float f0 = s0 + b0, f1 = s1 + b1, f2 = s2 + b2, f3 = s3 + b3;

        // ---- per-lane top-2 of its 4 sfc values
        float a = fmaxf(f0, f1), b = fminf(f0, f1);
        if (f2 > a) { b = a; a = f2; } else b = fmaxf(b, f2);
        if (f3 > a) { b = a; a = f3; } else b = fmaxf(b, f3);
        // ---- reduce top-2 across the 8 lanes of this group
#pragma unroll
        for (int m = 1; m <= 4; m <<= 1) {
            float oa = __shfl_xor(a, m);
            float ob = __shfl_xor(b, m);
            float na, nb;
            if (a >= oa) { na = a;  nb = fmaxf(oa, b); }
            else         { na = oa; nb = fmaxf(a, ob); }
            a = na; b = nb;
        }
        const float gsc = a + b;   // group score (fp32)

        // gather all 8 group scores to every lane
        float g0 = __shfl(gsc,  0), g1 = __shfl(gsc,  8);
        float g2 = __shfl(gsc, 16), g3 = __shfl(gsc, 24);
        float g4 = __shfl(gsc, 32), g5 = __shfl(gsc, 40);
        float g6 = __shfl(gsc, 48), g7 = __shfl(gsc, 56);

        // ---- top-4 groups (stable: lower index wins ties via strict >)
        unsigned gmask = 0;
#pragma unroll
        for (int r = 0; r < KGROUP; ++r) {
            float best = g0; int bg = 0;
            if (g1 > best) { best = g1; bg = 1; }
            if (g2 > best) { best = g2; bg = 2; }
            if (g3 > best) { best = g3; bg = 3; }
            if (g4 > best) { best = g4; bg = 4; }
            if (g5 > best) { best = g5; bg = 5; }
            if (g6 > best) { best = g6; bg = 6; }
            if (g7 > best) { best = g7; bg = 7; }
            gmask |= (1u << bg);
            g0 = (bg == 0) ? -1.f : g0;  g1 = (bg == 1) ? -1.f : g1;
            g2 = (bg == 2) ? -1.f : g2;  g3 = (bg == 3) ? -1.f : g3;
            g4 = (bg == 4) ? -1.f : g4;  g5 = (bg == 5) ? -1.f : g5;
            g6 = (bg == 6) ? -1.f : g6;  g7 = (bg == 7) ? -1.f : g7;
        }

        // ---- masked sfc (unselected groups -> 0.0, matching np.where)
        const int  myg  = lane >> 3;
        const bool keep = (gmask >> myg) & 1u;
        float v0 = keep ? f0 : 0.f, v1 = keep ? f1 : 0.f;
        float v2 = keep ? f2 : 0.f, v3 = keep ? f3 : 0.f;

        // ---- top-8: 8 rounds of 64-lane butterfly argmax, fp32 values,
        //      exact-equality ties -> lower expert index (stable top_k)
        int   isel[TOPK];
        float ssel[TOPK];
#pragma unroll
        for (int r = 0; r < TOPK; ++r) {
            float bv = v0; int bj = 0; float bs = s0;
            if (v1 > bv) { bv = v1; bj = 1; bs = s1; }
            if (v2 > bv) { bv = v2; bj = 2; bs = s2; }
            if (v3 > bv) { bv = v3; bj = 3; bs = s3; }
            float cv = bv; int ci = lane * 4 + bj; float cs = bs;
#pragma unroll
            for (int m = 1; m < 64; m <<= 1) {
                float ov = __shfl_xor(cv, m);
                int   oi = __shfl_xor(ci, m);
                float os = __shfl_xor(cs, m);
                if (ov > cv || (ov == cv && oi < ci)) { cv = ov; ci = oi; cs = os; }
            }
            isel[r] = ci; ssel[r] = cs;
            if ((ci >> 2) == lane) {       // owner removes the winner
                const int sl = ci & 3;
                v0 = (sl == 0) ? -1.f : v0;
                v1 = (sl == 1) ? -1.f : v1;
                v2 = (sl == 2) ? -1.f : v2;
                v3 = (sl == 3) ? -1.f : v3;
            }
        }

        // ---- normalize + scale in fp32: w = (w / (sum + 1e-20)) * 2.5
        // np pairwise 8-sum: ((w0+w1)+(w2+w3)) + ((w4+w5)+(w6+w7))
        const float sum = __fadd_rn(
            __fadd_rn(__fadd_rn(ssel[0], ssel[1]), __fadd_rn(ssel[2], ssel[3])),
            __fadd_rn(__fadd_rn(ssel[4], ssel[5]), __fadd_rn(ssel[6], ssel[7])));
        const float denom = __fadd_rn(sum, 1e-20f);
        if (lane == 0) {
#pragma unroll
            for (int r = 0; r < TOPK; ++r) {
                out_idx[(size_t)t * TOPK + r] = (float)isel[r];
                out_w  [(size_t)t * TOPK + r] =
                    __fmul_rn(__fdiv_rn(ssel[r], denom), 2.5f);
            }
        }
    }
}

extern "C" void kernel_launch(void* const* d_in, const int* in_sizes, int n_in,
                              void* d_out, int out_size, void* d_ws, size_t ws_size,
                              hipStream_t stream) {
    const float* hs = (const float*)d_in[0];
    const float* w  = (const float*)d_in[1];
    const float* b  = (const float*)d_in[2];
    const int E = in_sizes[2];          // 256
    const int H = in_sizes[1] / E;      // 2048
    const int T = in_sizes[0] / H;      // 16384
    (void)n_in; (void)d_ws; (void)ws_size; (void)out_size; (void)E; (void)H;

    dim3 grid(T / T_TILE);
    router_kernel<<<grid, 256, 0, stream>>>(hs, w, b, (float*)d_out, T);
}